// Round 4
// baseline (110.433 us; speedup 1.0000x reference)
//
#include <hip/hip_runtime.h>

#define BB 2
#define LL 1024
#define DD 1024
#define HH 16
#define NC 16
#define EPSF 1e-8f

typedef __attribute__((ext_vector_type(8))) short bf16x8;
typedef __attribute__((ext_vector_type(4))) float f32x4;
typedef unsigned short u16;

static __device__ inline u16 f2bf(float f) {
    unsigned int u = __builtin_bit_cast(unsigned int, f);
    u += 0x7fff + ((u >> 16) & 1);     // RNE
    return (u16)(u >> 16);
}

static __device__ inline void gload_lds16(const u16* g, u16* l) {
    __builtin_amdgcn_global_load_lds((const __attribute__((address_space(1))) void*)g,
                                     (__attribute__((address_space(3))) void*)l, 16, 0, 0);
}

// ---------------- fp32 -> bf16 convert: X (2M), Wq (1M), Wv (1M)
__global__ __launch_bounds__(256) void cvt_k(const float* __restrict__ X,
                                             const float* __restrict__ Wq,
                                             const float* __restrict__ Wv,
                                             u16* __restrict__ Xb,
                                             u16* __restrict__ Wqb,
                                             u16* __restrict__ Wvb)
{
    int i = (blockIdx.x * 256 + threadIdx.x) * 4;
    const float* s; u16* d; int off;
    if (i < 2*1024*1024)      { s = X;  d = Xb;  off = i; }
    else if (i < 3*1024*1024) { s = Wq; d = Wqb; off = i - 2*1024*1024; }
    else                      { s = Wv; d = Wvb; off = i - 3*1024*1024; }
    float4 v = *(const float4*)(s + off);
    ushort4 o;
    o.x = f2bf(v.x); o.y = f2bf(v.y); o.z = f2bf(v.z); o.w = f2bf(v.w);
    *(ushort4*)(d + off) = o;
}

// ---------------- bf16 MFMA GEMM + fused per-head RMSNorm, bf16 out.
// 128(M) x 64(N) tile, BK=32. Wave w owns rows w*32..w*32+31 x all 64 cols,
// so the d=64 RMS reduction is an in-register quad-shuffle (no LDS roundtrip).
__global__ __launch_bounds__(256) void gemm_fused(const u16* __restrict__ Xb,
                                                  const u16* __restrict__ Wqb,
                                                  const u16* __restrict__ Wvb,
                                                  const float* __restrict__ qw,
                                                  const float* __restrict__ vw,
                                                  u16* __restrict__ Qb,
                                                  u16* __restrict__ Vb)
{
    const int K = DD, N = DD;
    const u16* W = blockIdx.z ? Wvb : Wqb;
    const float* nw = blockIdx.z ? vw : qw;
    u16* Y = blockIdx.z ? Vb : Qb;
    __shared__ u16 As[128 * 32];
    __shared__ u16 Bs[64 * 32];

    const int tid = threadIdx.x, w = tid >> 6, lane = tid & 63;
    const int quad = lane >> 4, l16 = lane & 15;
    const int m0 = blockIdx.y * 128, n0 = blockIdx.x * 64;
    const int lrow = lane >> 2, lcol = (lane & 3) * 8;

    const u16* gA0 = Xb + (size_t)(m0 + w*16 + lrow) * K + lcol;
    const u16* gA1 = gA0 + (size_t)64 * K;
    const u16* gB0 = W + (size_t)(n0 + w*16 + lrow) * K + lcol;
    u16* lA0 = &As[(w*16) * 32];
    u16* lA1 = &As[(64 + w*16) * 32];
    u16* lB0 = &Bs[(w*16) * 32];

    f32x4 acc[2][4] = {};
    for (int k0 = 0; k0 < K; k0 += 32) {
        gload_lds16(gA0 + k0, lA0);
        gload_lds16(gA1 + k0, lA1);
        gload_lds16(gB0 + k0, lB0);
        __syncthreads();
        bf16x8 af[2], bfr[4];
        #pragma unroll
        for (int i = 0; i < 2; ++i)
            af[i] = *(const bf16x8*)&As[(w*32 + i*16 + l16) * 32 + quad*8];
        #pragma unroll
        for (int j = 0; j < 4; ++j)
            bfr[j] = *(const bf16x8*)&Bs[(j*16 + l16) * 32 + quad*8];
        #pragma unroll
        for (int i = 0; i < 2; ++i)
            #pragma unroll
            for (int j = 0; j < 4; ++j)
                acc[i][j] = __builtin_amdgcn_mfma_f32_16x16x32_bf16(af[i], bfr[j], acc[i][j], 0, 0, 0);
        __syncthreads();
    }

    // fused RMSNorm epilogue: row = m0 + w*32 + i*16 + quad*4 + r; col = j*16 + l16
    float wv[4];
    #pragma unroll
    for (int j = 0; j < 4; ++j) wv[j] = nw[n0 + j*16 + l16];
    #pragma unroll
    for (int i = 0; i < 2; ++i) {
        float ss[4];
        #pragma unroll
        for (int r = 0; r < 4; ++r) {
            float s = 0.f;
            #pragma unroll
            for (int j = 0; j < 4; ++j) s += acc[i][j][r] * acc[i][j][r];
            ss[r] = s;
        }
        #pragma unroll
        for (int off = 1; off < 16; off <<= 1)
            #pragma unroll
            for (int r = 0; r < 4; ++r) ss[r] += __shfl_xor(ss[r], off, 64);
        float sc[4];
        #pragma unroll
        for (int r = 0; r < 4; ++r) sc[r] = rsqrtf(ss[r] * (1.f/64.f) + EPSF);
        #pragma unroll
        for (int r = 0; r < 4; ++r) {
            u16* yp = Y + (size_t)(m0 + w*32 + i*16 + quad*4 + r) * N + n0;
            #pragma unroll
            for (int j = 0; j < 4; ++j)
                yp[j*16 + l16] = f2bf(acc[i][j][r] * sc[r] * wv[j]);
        }
    }
}

// ---------------- fused chunk-KV + exclusive prefix scan.
// grid 128 = (b,h) x (e-half, d-half). Block scans 16 chunks sequentially,
// MFMA-accumulates S^T[e][d] += V_c^T K_c, stores the EXCLUSIVE prefix (bf16)
// before each accumulation. Prefix lives in the MFMA accumulator.
__global__ __launch_bounds__(256) void kv_scan(const u16* __restrict__ Xb,
                                               const u16* __restrict__ Vb,
                                               u16* __restrict__ S)
{
    const int t = blockIdx.x & 3, bh = blockIdx.x >> 2;
    const int et = t & 1, dt = t >> 1;
    const int h = bh & 15, b = bh >> 4;
    __shared__ u16 Kt[32][72];   // [d_local][l]
    __shared__ u16 Vt[32][72];   // [e_local][l]
    const int tid = threadIdx.x, w = tid >> 6, lane = tid & 63;
    const int quad = lane >> 4, l16 = lane & 15;
    const int esub = (w & 1) * 16, dsub = (w >> 1) * 16;
    const int row = tid >> 2, q = tid & 3;   // row = l, q = 8-col group

    const u16* gK = Xb + (size_t)(b*LL + row) * DD + h*64 + dt*32 + q*8;
    const u16* gV = Vb + (size_t)(b*LL + row) * DD + h*64 + et*32 + q*8;

    ushort4 kr[2], vr[2];
    kr[0] = *(const ushort4*)(gK);     kr[1] = *(const ushort4*)(gK + 4);
    vr[0] = *(const ushort4*)(gV);     vr[1] = *(const ushort4*)(gV + 4);

    f32x4 acc = {};
    for (int c = 0; c < NC; ++c) {
        #pragma unroll
        for (int i = 0; i < 4; ++i) {
            Kt[q*8 + i][row]     = ((const u16*)&kr[0])[i];
            Kt[q*8 + 4 + i][row] = ((const u16*)&kr[1])[i];
            Vt[q*8 + i][row]     = ((const u16*)&vr[0])[i];
            Vt[q*8 + 4 + i][row] = ((const u16*)&vr[1])[i];
        }
        __syncthreads();
        if (c + 1 < NC) {   // software-pipelined next-chunk load
            const u16* nK = gK + (size_t)(c+1)*64*DD;
            const u16* nV = gV + (size_t)(c+1)*64*DD;
            kr[0] = *(const ushort4*)(nK); kr[1] = *(const ushort4*)(nK + 4);
            vr[0] = *(const ushort4*)(nV); vr[1] = *(const ushort4*)(nV + 4);
        }
        // store exclusive prefix (before accumulating this chunk)
        u16* Sp = S + ((size_t)bh * NC + c) * 4096;
        #pragma unroll
        for (int r = 0; r < 4; ++r)
            Sp[(et*32 + esub + quad*4 + r) * 64 + dt*32 + dsub + l16] = f2bf(acc[r]);
        // accumulate: S^T[e][d] += sum_l V[l][e] K[l][d]
        #pragma unroll
        for (int k0 = 0; k0 < 64; k0 += 32) {
            bf16x8 av = *(const bf16x8*)&Vt[esub + l16][k0 + quad*8];
            bf16x8 bv = *(const bf16x8*)&Kt[dsub + l16][k0 + quad*8];
            acc = __builtin_amdgcn_mfma_f32_16x16x32_bf16(av, bv, acc, 0, 0, 0);
        }
        __syncthreads();
    }
}

// ---------------- out = tril(Q K^T) @ V + Q @ S0, per chunk, MFMA.
// Ps (masked P, bf16) aliases Ks (dead after the P phase). S is bf16.
__global__ __launch_bounds__(256) void out_k(const u16* __restrict__ Xb,
                                             const u16* __restrict__ Qb,
                                             const u16* __restrict__ Vb,
                                             const u16* __restrict__ S,
                                             float* __restrict__ out)
{
    const int c = blockIdx.x & 15, bh = blockIdx.x >> 4;
    const int h = bh & 15, b = bh >> 4;
    __shared__ u16 Qs[64][72];   // [l][d]
    __shared__ u16 Ks[64][72];   // [l'][d] -> later Ps [l][l']
    __shared__ u16 Vt[64][72];   // [e][l']
    __shared__ u16 St[64][72];   // [e][d]  (S^T prefix, bf16)
    const int tid = threadIdx.x;
    {
        const int row = tid >> 2, q = tid & 3;
        size_t gbase = (size_t)(b*LL + c*64 + row) * DD + h*64 + q*16;
        u16 vv[16];
        #pragma unroll
        for (int i = 0; i < 16; i += 4) {
            *(ushort4*)&Qs[row][q*16 + i] = *(const ushort4*)(Qb + gbase + i);
            *(ushort4*)&Ks[row][q*16 + i] = *(const ushort4*)(Xb + gbase + i);
            *(ushort4*)&vv[i] = *(const ushort4*)(Vb + gbase + i);
        }
        #pragma unroll
        for (int i = 0; i < 16; ++i)
            Vt[q*16 + i][row] = vv[i];
        const u16* sp = S + ((size_t)bh * NC + c) * 4096 + row*64 + q*16;
        #pragma unroll
        for (int i = 0; i < 16; i += 4)
            *(ushort4*)&St[row][q*16 + i] = *(const ushort4*)(sp + i);
    }
    __syncthreads();
    const int w = tid >> 6, lane = tid & 63, quad = lane >> 4, l16 = lane & 15;
    const int mo = (w & 1) * 32, no = (w >> 1) * 32;

    // P = Q K^T, causal-masked, bf16
    f32x4 pacc[2][2] = {};
    #pragma unroll
    for (int k0 = 0; k0 < 64; k0 += 32) {
        bf16x8 aq[2], bk[2];
        #pragma unroll
        for (int i = 0; i < 2; ++i)
            aq[i] = *(const bf16x8*)&Qs[mo + i*16 + l16][k0 + quad*8];
        #pragma unroll
        for (int j = 0; j < 2; ++j)
            bk[j] = *(const bf16x8*)&Ks[no + j*16 + l16][k0 + quad*8];
        #pragma unroll
        for (int i = 0; i < 2; ++i)
            #pragma unroll
            for (int j = 0; j < 2; ++j)
                pacc[i][j] = __builtin_amdgcn_mfma_f32_16x16x32_bf16(aq[i], bk[j], pacc[i][j], 0, 0, 0);
    }
    __syncthreads();   // everyone done reading Ks
    #pragma unroll
    for (int i = 0; i < 2; ++i)
        #pragma unroll
        for (int j = 0; j < 2; ++j)
            #pragma unroll
            for (int r = 0; r < 4; ++r) {
                int l  = mo + i*16 + quad*4 + r;
                int lp = no + j*16 + l16;
                Ks[l][lp] = (lp <= l) ? f2bf(pacc[i][j][r]) : (u16)0;   // Ps
            }
    __syncthreads();

    // O = P @ V + Q @ S0
    f32x4 acc[2][2] = {};
    #pragma unroll
    for (int k0 = 0; k0 < 64; k0 += 32) {
        bf16x8 a1[2], b1[2], a2[2], b2[2];
        #pragma unroll
        for (int i = 0; i < 2; ++i) {
            a1[i] = *(const bf16x8*)&Ks[mo + i*16 + l16][k0 + quad*8];  // Ps
            a2[i] = *(const bf16x8*)&Qs[mo + i*16 + l16][k0 + quad*8];
        }
        #pragma unroll
        for (int j = 0; j < 2; ++j) {
            b1[j] = *(const bf16x8*)&Vt[no + j*16 + l16][k0 + quad*8];
            b2[j] = *(const bf16x8*)&St[no + j*16 + l16][k0 + quad*8];
        }
        #pragma unroll
        for (int i = 0; i < 2; ++i)
            #pragma unroll
            for (int j = 0; j < 2; ++j) {
                acc[i][j] = __builtin_amdgcn_mfma_f32_16x16x32_bf16(a1[i], b1[j], acc[i][j], 0, 0, 0);
                acc[i][j] = __builtin_amdgcn_mfma_f32_16x16x32_bf16(a2[i], b2[j], acc[i][j], 0, 0, 0);
            }
    }
    float* op = out + (size_t)(b*LL + c*64) * DD + h*64;
    #pragma unroll
    for (int i = 0; i < 2; ++i)
        #pragma unroll
        for (int j = 0; j < 2; ++j)
            #pragma unroll
            for (int r = 0; r < 4; ++r)
                op[(size_t)(mo + i*16 + quad*4 + r) * DD + no + j*16 + l16] = acc[i][j][r];
}

extern "C" void kernel_launch(void* const* d_in, const int* in_sizes, int n_in,
                              void* d_out, int out_size, void* d_ws, size_t ws_size,
                              hipStream_t stream) {
    const float* X  = (const float*)d_in[0];
    const float* Wq = (const float*)d_in[1];
    const float* Wv = (const float*)d_in[2];
    const float* qw = (const float*)d_in[3];
    const float* vw = (const float*)d_in[4];
    float* out = (float*)d_out;

    u16* Xb  = (u16*)d_ws;                        // 2M u16
    u16* Wqb = Xb  + (size_t)2*1024*1024;         // 1M
    u16* Wvb = Wqb + (size_t)1024*1024;           // 1M
    u16* Qb  = Wvb + (size_t)1024*1024;           // 2M
    u16* Vb  = Qb  + (size_t)2*1024*1024;         // 2M
    u16* S   = Vb  + (size_t)2*1024*1024;         // 2M u16 (bf16 prefix states)

    cvt_k<<<4096, 256, 0, stream>>>(X, Wq, Wv, Xb, Wqb, Wvb);
    gemm_fused<<<dim3(16, 16, 2), 256, 0, stream>>>(Xb, Wqb, Wvb, qw, vw, Qb, Vb);
    kv_scan<<<128, 256, 0, stream>>>(Xb, Vb, S);
    out_k<<<BB*HH*NC, 256, 0, stream>>>(Xb, Qb, Vb, S, out);
}

// Round 5
// 106.216 us; speedup vs baseline: 1.0397x; 1.0397x over previous
//
#include <hip/hip_runtime.h>

#define BB 2
#define LL 1024
#define DD 1024
#define HH 16
#define NC 16
#define EPSF 1e-8f

typedef __attribute__((ext_vector_type(8))) short bf16x8;
typedef __attribute__((ext_vector_type(4))) float f32x4;
typedef unsigned short u16;

static __device__ inline u16 f2bf(float f) {
    unsigned int u = __builtin_bit_cast(unsigned int, f);
    u += 0x7fff + ((u >> 16) & 1);     // RNE
    return (u16)(u >> 16);
}

static __device__ inline void gload_lds16(const u16* g, u16* l) {
    __builtin_amdgcn_global_load_lds((const __attribute__((address_space(1))) void*)g,
                                     (__attribute__((address_space(3))) void*)l, 16, 0, 0);
}

// ---------------- fp32 -> bf16 convert: X (2M), Wq (1M), Wv (1M)
__global__ __launch_bounds__(256) void cvt_k(const float* __restrict__ X,
                                             const float* __restrict__ Wq,
                                             const float* __restrict__ Wv,
                                             u16* __restrict__ Xb,
                                             u16* __restrict__ Wqb,
                                             u16* __restrict__ Wvb)
{
    int i = (blockIdx.x * 256 + threadIdx.x) * 4;
    const float* s; u16* d; int off;
    if (i < 2*1024*1024)      { s = X;  d = Xb;  off = i; }
    else if (i < 3*1024*1024) { s = Wq; d = Wqb; off = i - 2*1024*1024; }
    else                      { s = Wv; d = Wvb; off = i - 3*1024*1024; }
    float4 v = *(const float4*)(s + off);
    ushort4 o;
    o.x = f2bf(v.x); o.y = f2bf(v.y); o.z = f2bf(v.z); o.w = f2bf(v.w);
    *(ushort4*)(d + off) = o;
}

// ---------------- bf16 MFMA GEMM + fused per-head RMSNorm, bf16 out.
// 128(M) x 64(N) tile, BK=64 via two ping LDS slices -> 16 K-steps, half the
// barrier drains of BK=32. Wave w owns rows w*32..+31 x all 64 cols, so the
// d=64 RMS reduction is an in-register quad-shuffle.
__global__ __launch_bounds__(256) void gemm_fused(const u16* __restrict__ Xb,
                                                  const u16* __restrict__ Wqb,
                                                  const u16* __restrict__ Wvb,
                                                  const float* __restrict__ qw,
                                                  const float* __restrict__ vw,
                                                  u16* __restrict__ Qb,
                                                  u16* __restrict__ Vb)
{
    const int K = DD, N = DD;
    const u16* W = blockIdx.z ? Wvb : Wqb;
    const float* nw = blockIdx.z ? vw : qw;
    u16* Y = blockIdx.z ? Vb : Qb;
    __shared__ u16 As0[128 * 32], As1[128 * 32];
    __shared__ u16 Bs0[64 * 32],  Bs1[64 * 32];

    const int tid = threadIdx.x, w = tid >> 6, lane = tid & 63;
    const int quad = lane >> 4, l16 = lane & 15;
    const int m0 = blockIdx.y * 128, n0 = blockIdx.x * 64;
    const int lrow = lane >> 2, lcol = (lane & 3) * 8;

    const u16* gA0 = Xb + (size_t)(m0 + w*16 + lrow) * K + lcol;
    const u16* gA1 = gA0 + (size_t)64 * K;
    const u16* gB0 = W + (size_t)(n0 + w*16 + lrow) * K + lcol;
    u16* lA0_0 = &As0[(w*16) * 32];      u16* lA0_1 = &As1[(w*16) * 32];
    u16* lA1_0 = &As0[(64 + w*16) * 32]; u16* lA1_1 = &As1[(64 + w*16) * 32];
    u16* lB0_0 = &Bs0[(w*16) * 32];      u16* lB0_1 = &Bs1[(w*16) * 32];

    f32x4 acc[2][4] = {};
    for (int k0 = 0; k0 < K; k0 += 64) {
        gload_lds16(gA0 + k0,      lA0_0);
        gload_lds16(gA0 + k0 + 32, lA0_1);
        gload_lds16(gA1 + k0,      lA1_0);
        gload_lds16(gA1 + k0 + 32, lA1_1);
        gload_lds16(gB0 + k0,      lB0_0);
        gload_lds16(gB0 + k0 + 32, lB0_1);
        __syncthreads();
        #pragma unroll
        for (int hh = 0; hh < 2; ++hh) {
            const u16* Ah = hh ? As1 : As0;
            const u16* Bh = hh ? Bs1 : Bs0;
            bf16x8 af[2], bfr[4];
            #pragma unroll
            for (int i = 0; i < 2; ++i)
                af[i] = *(const bf16x8*)&Ah[(w*32 + i*16 + l16) * 32 + quad*8];
            #pragma unroll
            for (int j = 0; j < 4; ++j)
                bfr[j] = *(const bf16x8*)&Bh[(j*16 + l16) * 32 + quad*8];
            #pragma unroll
            for (int i = 0; i < 2; ++i)
                #pragma unroll
                for (int j = 0; j < 4; ++j)
                    acc[i][j] = __builtin_amdgcn_mfma_f32_16x16x32_bf16(af[i], bfr[j], acc[i][j], 0, 0, 0);
        }
        __syncthreads();
    }

    // fused RMSNorm epilogue: row = m0 + w*32 + i*16 + quad*4 + r; col = j*16 + l16
    float wv[4];
    #pragma unroll
    for (int j = 0; j < 4; ++j) wv[j] = nw[n0 + j*16 + l16];
    #pragma unroll
    for (int i = 0; i < 2; ++i) {
        float ss[4];
        #pragma unroll
        for (int r = 0; r < 4; ++r) {
            float s = 0.f;
            #pragma unroll
            for (int j = 0; j < 4; ++j) s += acc[i][j][r] * acc[i][j][r];
            ss[r] = s;
        }
        #pragma unroll
        for (int off = 1; off < 16; off <<= 1)
            #pragma unroll
            for (int r = 0; r < 4; ++r) ss[r] += __shfl_xor(ss[r], off, 64);
        float sc[4];
        #pragma unroll
        for (int r = 0; r < 4; ++r) sc[r] = rsqrtf(ss[r] * (1.f/64.f) + EPSF);
        #pragma unroll
        for (int r = 0; r < 4; ++r) {
            u16* yp = Y + (size_t)(m0 + w*32 + i*16 + quad*4 + r) * N + n0;
            #pragma unroll
            for (int j = 0; j < 4; ++j)
                yp[j*16 + l16] = f2bf(acc[i][j][r] * sc[r] * wv[j]);
        }
    }
}

// ---------------- fused chunk-KV + exclusive prefix scan, double-buffered.
// grid 128 = (b,h) x (e-half, d-half). One barrier per chunk iteration.
// S stored as bf16 in flat MFMA C-layout: offset = t*1024 + w*256 + r*64 + lane
//   e = (t&1)*32 + (w&1)*16 + (lane>>4)*4 + r ; d = (t>>1)*32 + ((w>>1)&1)*16 + (lane&15)
__global__ __launch_bounds__(256) void kv_scan(const u16* __restrict__ Xb,
                                               const u16* __restrict__ Vb,
                                               u16* __restrict__ S)
{
    const int t = blockIdx.x & 3, bh = blockIdx.x >> 2;
    const int et = t & 1, dt = t >> 1;
    const int h = bh & 15, b = bh >> 4;
    __shared__ u16 Kt[2][32][72];   // [buf][d_local][l]
    __shared__ u16 Vt[2][32][72];   // [buf][e_local][l]
    const int tid = threadIdx.x, w = tid >> 6, lane = tid & 63;
    const int quad = lane >> 4, l16 = lane & 15;
    const int esub = (w & 1) * 16, dsub = (w >> 1) * 16;
    // staging: threads 0..127 load K (64 rows x 32 cols), 128..255 load V.
    const int half = tid >> 7, hrow = (tid & 127) >> 1, hq = tid & 1;
    const u16* gsrc = (half ? Vb : Xb) + (size_t)(b*LL + hrow) * DD
                      + h*64 + (half ? et : dt) * 32 + hq*16;
    u16 (*Tb)[32][72] = half ? Vt : Kt;
    ushort4 rr[4];

    auto loadc = [&](int c) {
        const u16* p = gsrc + (size_t)c * 64 * DD;
        rr[0] = *(const ushort4*)(p);      rr[1] = *(const ushort4*)(p + 4);
        rr[2] = *(const ushort4*)(p + 8);  rr[3] = *(const ushort4*)(p + 12);
    };
    auto writec = [&](int buf) {
        #pragma unroll
        for (int i = 0; i < 16; ++i)
            Tb[buf][hq*16 + i][hrow] = ((const u16*)rr)[i];
    };

    loadc(0); writec(0); loadc(1);
    __syncthreads();
    f32x4 acc = {};
    for (int c = 0; c < NC; ++c) {
        const int cur = c & 1;
        if (c + 1 < NC) writec(1 - cur);
        if (c + 2 < NC) loadc(c + 2);
        // exclusive prefix store, coalesced (128B per r)
        u16* Sp = S + (((size_t)(bh*NC + c)) << 12) + t*1024 + w*256;
        #pragma unroll
        for (int r = 0; r < 4; ++r) Sp[r*64 + lane] = f2bf(acc[r]);
        // accumulate: S^T[e][d] += sum_l V[l][e] K[l][d]
        #pragma unroll
        for (int k0 = 0; k0 < 64; k0 += 32) {
            bf16x8 av = *(const bf16x8*)&Vt[cur][esub + l16][k0 + quad*8];
            bf16x8 bv = *(const bf16x8*)&Kt[cur][dsub + l16][k0 + quad*8];
            acc = __builtin_amdgcn_mfma_f32_16x16x32_bf16(av, bv, acc, 0, 0, 0);
        }
        __syncthreads();
    }
}

// ---------------- out = tril(Q K^T) @ V + Q @ S0, per chunk, MFMA.
__global__ __launch_bounds__(256) void out_k(const u16* __restrict__ Xb,
                                             const u16* __restrict__ Qb,
                                             const u16* __restrict__ Vb,
                                             const u16* __restrict__ S,
                                             float* __restrict__ out)
{
    const int c = blockIdx.x & 15, bh = blockIdx.x >> 4;
    const int h = bh & 15, b = bh >> 4;
    __shared__ u16 Qs[64][72];   // [l][d]
    __shared__ u16 Ks[64][72];   // [l'][d] -> later Ps [l][l']
    __shared__ u16 Vt[64][72];   // [e][l']
    __shared__ u16 St[64][72];   // [e][d]  (S^T prefix, bf16)
    const int tid = threadIdx.x;
    {
        const int row = tid >> 2, q = tid & 3;
        size_t gbase = (size_t)(b*LL + c*64 + row) * DD + h*64 + q*16;
        u16 vv[16];
        #pragma unroll
        for (int i = 0; i < 16; i += 4) {
            *(ushort4*)&Qs[row][q*16 + i] = *(const ushort4*)(Qb + gbase + i);
            *(ushort4*)&Ks[row][q*16 + i] = *(const ushort4*)(Xb + gbase + i);
            *(ushort4*)&vv[i] = *(const ushort4*)(Vb + gbase + i);
        }
        #pragma unroll
        for (int i = 0; i < 16; ++i)
            Vt[q*16 + i][row] = vv[i];
        // S: flat C-layout decode, fully coalesced 16B reads
        const u16* Sc = S + (((size_t)(bh*NC + c)) << 12);
        #pragma unroll
        for (int j = 0; j < 4; ++j) {
            int f = (tid + j*256) * 4;
            ushort4 sv = *(const ushort4*)(Sc + f);
            int tt = f >> 10, ww = (f >> 8) & 3, rr_ = (f >> 6) & 3, ln = f & 63;
            int e = (tt & 1)*32 + (ww & 1)*16 + (ln >> 4)*4 + rr_;
            int d = (tt >> 1)*32 + ((ww >> 1) & 1)*16 + (ln & 15);
            *(ushort4*)&St[e][d] = sv;
        }
    }
    __syncthreads();
    const int w = tid >> 6, lane = tid & 63, quad = lane >> 4, l16 = lane & 15;
    const int mo = (w & 1) * 32, no = (w >> 1) * 32;

    // P = Q K^T, causal-masked, bf16
    f32x4 pacc[2][2] = {};
    #pragma unroll
    for (int k0 = 0; k0 < 64; k0 += 32) {
        bf16x8 aq[2], bk[2];
        #pragma unroll
        for (int i = 0; i < 2; ++i)
            aq[i] = *(const bf16x8*)&Qs[mo + i*16 + l16][k0 + quad*8];
        #pragma unroll
        for (int j = 0; j < 2; ++j)
            bk[j] = *(const bf16x8*)&Ks[no + j*16 + l16][k0 + quad*8];
        #pragma unroll
        for (int i = 0; i < 2; ++i)
            #pragma unroll
            for (int j = 0; j < 2; ++j)
                pacc[i][j] = __builtin_amdgcn_mfma_f32_16x16x32_bf16(aq[i], bk[j], pacc[i][j], 0, 0, 0);
    }
    __syncthreads();   // everyone done reading Ks
    #pragma unroll
    for (int i = 0; i < 2; ++i)
        #pragma unroll
        for (int j = 0; j < 2; ++j)
            #pragma unroll
            for (int r = 0; r < 4; ++r) {
                int l  = mo + i*16 + quad*4 + r;
                int lp = no + j*16 + l16;
                Ks[l][lp] = (lp <= l) ? f2bf(pacc[i][j][r]) : (u16)0;   // Ps
            }
    __syncthreads();

    // O = P @ V + Q @ S0
    f32x4 acc[2][2] = {};
    #pragma unroll
    for (int k0 = 0; k0 < 64; k0 += 32) {
        bf16x8 a1[2], b1[2], a2[2], b2[2];
        #pragma unroll
        for (int i = 0; i < 2; ++i) {
            a1[i] = *(const bf16x8*)&Ks[mo + i*16 + l16][k0 + quad*8];  // Ps
            a2[i] = *(const bf16x8*)&Qs[mo + i*16 + l16][k0 + quad*8];
        }
        #pragma unroll
        for (int j = 0; j < 2; ++j) {
            b1[j] = *(const bf16x8*)&Vt[no + j*16 + l16][k0 + quad*8];
            b2[j] = *(const bf16x8*)&St[no + j*16 + l16][k0 + quad*8];
        }
        #pragma unroll
        for (int i = 0; i < 2; ++i)
            #pragma unroll
            for (int j = 0; j < 2; ++j) {
                acc[i][j] = __builtin_amdgcn_mfma_f32_16x16x32_bf16(a1[i], b1[j], acc[i][j], 0, 0, 0);
                acc[i][j] = __builtin_amdgcn_mfma_f32_16x16x32_bf16(a2[i], b2[j], acc[i][j], 0, 0, 0);
            }
    }
    float* op = out + (size_t)(b*LL + c*64) * DD + h*64;
    #pragma unroll
    for (int i = 0; i < 2; ++i)
        #pragma unroll
        for (int j = 0; j < 2; ++j)
            #pragma unroll
            for (int r = 0; r < 4; ++r)
                op[(size_t)(mo + i*16 + quad*4 + r) * DD + no + j*16 + l16] = acc[i][j][r];
}

extern "C" void kernel_launch(void* const* d_in, const int* in_sizes, int n_in,
                              void* d_out, int out_size, void* d_ws, size_t ws_size,
                              hipStream_t stream) {
    const float* X  = (const float*)d_in[0];
    const float* Wq = (const float*)d_in[1];
    const float* Wv = (const float*)d_in[2];
    const float* qw = (const float*)d_in[3];
    const float* vw = (const float*)d_in[4];
    float* out = (float*)d_out;

    u16* Xb  = (u16*)d_ws;                        // 2M u16
    u16* Wqb = Xb  + (size_t)2*1024*1024;         // 1M
    u16* Wvb = Wqb + (size_t)1024*1024;           // 1M
    u16* Qb  = Wvb + (size_t)1024*1024;           // 2M
    u16* Vb  = Qb  + (size_t)2*1024*1024;         // 2M
    u16* S   = Vb  + (size_t)2*1024*1024;         // 2M u16 (bf16 prefix states)

    cvt_k<<<4096, 256, 0, stream>>>(X, Wq, Wv, Xb, Wqb, Wvb);
    gemm_fused<<<dim3(16, 16, 2), 256, 0, stream>>>(Xb, Wqb, Wvb, qw, vw, Qb, Vb);
    kv_scan<<<128, 256, 0, stream>>>(Xb, Vb, S);
    out_k<<<BB*HH*NC, 256, 0, stream>>>(Xb, Qb, Vb, S, out);
}